// Round 1
// baseline (2138.083 us; speedup 1.0000x reference)
//
#include <hip/hip_runtime.h>

// Problem constants (B=4, N=512, D=128, DH=64)
#define BATCH 4
#define NSEQ  512
#define DIN   128
#define DHO   64
#define NROWS (BATCH * NSEQ * NSEQ)   // 1,048,576 (b,i,j) rows
#define ROWS_PER_WAVE 128
#define K2_WAVES (NROWS / ROWS_PER_WAVE)    // 8192
#define K2_BLOCKS (K2_WAVES / 4)            // 2048 blocks of 256 threads

// Workspace layout (float offsets)
#define OFF_Q   0
#define OFF_K   (1 * BATCH * NSEQ * DHO)
#define OFF_V   (2 * BATCH * NSEQ * DHO)
#define OFF_NI  (3 * BATCH * NSEQ * DHO)
#define OFF_NJ  (4 * BATCH * NSEQ * DHO)
#define OFF_S   (5 * BATCH * NSEQ * DHO)            // att logits [B,N,N] = 4 MB
#define OFF_CM  (OFF_S + BATCH * NSEQ * NSEQ)       // column max  [B,N]
#define OFF_CRS (OFF_CM + BATCH * NSEQ)             // column 1/sum [B,N]

// ---------------------------------------------------------------------------
// Kernel 1: Q,K,V,Ni,Nj projections of h.  One block per (b,n) row,
// 320 threads = 5 waves; wave p handles projection p, lane = output channel.
// ---------------------------------------------------------------------------
__global__ void k1_proj(const float* __restrict__ h,
                        const float* __restrict__ Wq, const float* __restrict__ bq,
                        const float* __restrict__ Wk, const float* __restrict__ bk,
                        const float* __restrict__ Wv, const float* __restrict__ bv,
                        const float* __restrict__ Wni, const float* __restrict__ bni,
                        const float* __restrict__ Wnj, const float* __restrict__ bnj,
                        float* __restrict__ Qw, float* __restrict__ Kw,
                        float* __restrict__ Vw, float* __restrict__ Niw,
                        float* __restrict__ Njw) {
  __shared__ float hrow[DIN];
  const int row = blockIdx.x;            // b*N + n
  const int t = threadIdx.x;             // 0..319
  if (t < DIN) hrow[t] = h[(long)row * DIN + t];
  __syncthreads();
  const int p = t >> 6;                  // projection / wave id
  const int hh = t & 63;                 // output channel
  const float* W; const float* bias; float* outp;
  switch (p) {
    case 0:  W = Wq;  bias = bq;  outp = Qw;  break;
    case 1:  W = Wk;  bias = bk;  outp = Kw;  break;
    case 2:  W = Wv;  bias = bv;  outp = Vw;  break;
    case 3:  W = Wni; bias = bni; outp = Niw; break;
    default: W = Wnj; bias = bnj; outp = Njw; break;
  }
  const float* wr = W + hh * DIN;
  float acc = 0.f;
  #pragma unroll
  for (int d = 0; d < DIN; d += 4) {
    const float4 w4 = *reinterpret_cast<const float4*>(wr + d);
    acc = fmaf(w4.x, hrow[d],     acc);
    acc = fmaf(w4.y, hrow[d + 1], acc);
    acc = fmaf(w4.z, hrow[d + 2], acc);
    acc = fmaf(w4.w, hrow[d + 3], acc);
  }
  outp[(long)row * DHO + hh] = acc + bias[hh];
}

// ---------------------------------------------------------------------------
// Kernel 2 (dominant): fused E-linear + bias + Ni + Nj  -> e_out (streamed),
// plus att logits S[b,i,j] = sum_h Q*e_out*K / 8.
// One wave per row stream (128 consecutive rows, fixed (b,i)).
// Lane h holds We[h][0:128] in 128 VGPRs; the e row is staged in a
// wave-private LDS buffer and consumed by uniform ds_read_b128 broadcasts.
// 2 rows per iteration, next pair prefetched during compute.
// ---------------------------------------------------------------------------
__global__ void __launch_bounds__(256)
k2_eout_att(const float* __restrict__ e,
            const float* __restrict__ We, const float* __restrict__ be,
            const float* __restrict__ Qw, const float* __restrict__ Kw,
            const float* __restrict__ Niw, const float* __restrict__ Njw,
            float* __restrict__ eout, float* __restrict__ Sl) {
  __shared__ float ebuf[4][2][DIN];      // per-wave double row buffer (4 KB)
  const int w    = threadIdx.x >> 6;
  const int lane = threadIdx.x & 63;
  const int wave = blockIdx.x * 4 + w;
  const long r0  = (long)wave * ROWS_PER_WAVE;
  const int b  = (int)(r0 >> 18);
  const int i  = (int)((r0 >> 9) & (NSEQ - 1));   // fixed over the 128-row chunk
  const int j0 = (int)(r0 & (NSEQ - 1));

  // We row for this lane -> registers (reused for 128 rows)
  float we[DIN];
  {
    const float* wr = We + lane * DIN;
    #pragma unroll
    for (int d = 0; d < DIN; d += 4) {
      const float4 w4 = *reinterpret_cast<const float4*>(wr + d);
      we[d] = w4.x; we[d + 1] = w4.y; we[d + 2] = w4.z; we[d + 3] = w4.w;
    }
  }
  const float biasv = be[lane];
  const float qv  = Qw[((long)b * NSEQ + i) * DHO + lane];
  const float niv = Niw[((long)b * NSEQ + i) * DHO + lane];

  const float2* e2 = reinterpret_cast<const float2*>(e + r0 * DIN);
  float2 ev0 = e2[lane];            // prefetch pair 0
  float2 ev1 = e2[64 + lane];
  float* eb0 = &ebuf[w][0][0];
  float* eb1 = &ebuf[w][1][0];

  for (int rr = 0; rr < ROWS_PER_WAVE; rr += 2) {
    const long r = r0 + rr;
    const int j = j0 + rr;
    // stage current pair into wave-private LDS
    reinterpret_cast<float2*>(eb0)[lane] = ev0;
    reinterpret_cast<float2*>(eb1)[lane] = ev1;
    // prefetch next pair (hides HBM latency under the dot products)
    if (rr + 2 < ROWS_PER_WAVE) {
      ev0 = e2[(rr + 2) * 64 + lane];
      ev1 = e2[(rr + 3) * 64 + lane];
    }
    // per-row small vectors (L1/L2 resident)
    const float kv0  = Kw[((long)b * NSEQ + j) * DHO + lane];
    const float kv1  = Kw[((long)b * NSEQ + j + 1) * DHO + lane];
    const float njv0 = Njw[((long)b * NSEQ + j) * DHO + lane];
    const float njv1 = Njw[((long)b * NSEQ + j + 1) * DHO + lane];
    // same-wave LDS write->read: drain lgkmcnt (no block barrier needed,
    // buffers are wave-private; LDS ops of one wave complete in order)
    asm volatile("s_waitcnt lgkmcnt(0)" ::: "memory");

    float acc0 = 0.f, acc1 = 0.f;
    #pragma unroll
    for (int d = 0; d < DIN; d += 4) {
      const float4 a4 = *reinterpret_cast<const float4*>(eb0 + d);  // broadcast
      const float4 c4 = *reinterpret_cast<const float4*>(eb1 + d);  // broadcast
      acc0 = fmaf(a4.x, we[d],     acc0);
      acc0 = fmaf(a4.y, we[d + 1], acc0);
      acc0 = fmaf(a4.z, we[d + 2], acc0);
      acc0 = fmaf(a4.w, we[d + 3], acc0);
      acc1 = fmaf(c4.x, we[d],     acc1);
      acc1 = fmaf(c4.y, we[d + 1], acc1);
      acc1 = fmaf(c4.z, we[d + 2], acc1);
      acc1 = fmaf(c4.w, we[d + 3], acc1);
    }
    const float eo0 = acc0 + biasv + niv + njv0;
    const float eo1 = acc1 + biasv + niv + njv1;
    // e_out is write-once, never re-read: nontemporal store
    __builtin_nontemporal_store(eo0, eout + r * DHO + lane);
    __builtin_nontemporal_store(eo1, eout + (r + 1) * DHO + lane);

    // att logit: reduce eo*q*k over the 64 channels
    float t0 = eo0 * qv * kv0;
    float t1 = eo1 * qv * kv1;
    #pragma unroll
    for (int off = 32; off > 0; off >>= 1) {
      t0 += __shfl_xor(t0, off, 64);
      t1 += __shfl_xor(t1, off, 64);
    }
    if (lane == 0) {
      Sl[r]     = t0 * 0.125f;   // 1/sqrt(64)
      Sl[r + 1] = t1 * 0.125f;
    }
  }
}

// ---------------------------------------------------------------------------
// Kernel 3: softmax stats over axis i (columns of S[b,:,j]).
// Grid: B * (N/16) blocks, block = 256 threads = (16 j) x (16 i-partials).
// ---------------------------------------------------------------------------
__global__ void k3_colstats(const float* __restrict__ Sl,
                            float* __restrict__ colm, float* __restrict__ colrs) {
  const int b  = blockIdx.x >> 5;            // N/16 = 32 chunks per batch
  const int j0 = (blockIdx.x & 31) << 4;
  const int jl = threadIdx.x & 15;
  const int ip = threadIdx.x >> 4;           // 0..15
  const int j = j0 + jl;
  const float* Sb = Sl + ((long)b << 18);    // b * N * N
  float m = -1e30f, s = 0.f;
  for (int i = ip; i < NSEQ; i += 16) {
    const float x = Sb[(long)i * NSEQ + j];
    const float nm = fmaxf(m, x);
    s = s * __expf(m - nm) + __expf(x - nm);
    m = nm;
  }
  __shared__ float ms[16][16], ss[16][16];
  ms[ip][jl] = m; ss[ip][jl] = s;
  __syncthreads();
  if (ip == 0) {
    float M = -1e30f, Sum = 0.f;
    #pragma unroll
    for (int k = 0; k < 16; ++k) {
      const float mk = ms[k][jl], sk = ss[k][jl];
      const float nm = fmaxf(M, mk);
      Sum = Sum * __expf(M - nm) + sk * __expf(mk - nm);
      M = nm;
    }
    colm[(long)b * NSEQ + j]  = M;
    colrs[(long)b * NSEQ + j] = 1.0f / Sum;
  }
}

// ---------------------------------------------------------------------------
// Kernel 4: h_out[b,i,d] = sum_j softmax(S)[b,i,j] * V[b,j,d].
// One wave per output row (b,i); lane = d. S row + column stats staged in LDS.
// ---------------------------------------------------------------------------
__global__ void k4_hout(const float* __restrict__ Sl,
                        const float* __restrict__ colm, const float* __restrict__ colrs,
                        const float* __restrict__ Vw, float* __restrict__ hout) {
  __shared__ float srow[4][NSEQ];
  __shared__ float mrow[NSEQ], rsrow[NSEQ];
  const int w    = threadIdx.x >> 6;
  const int lane = threadIdx.x & 63;
  const int row  = blockIdx.x * 4 + w;       // b*N + i  (block never straddles b)
  const int b    = row >> 9;
  for (int t = threadIdx.x; t < NSEQ; t += 256) {
    mrow[t]  = colm[(long)b * NSEQ + t];
    rsrow[t] = colrs[(long)b * NSEQ + t];
  }
  const float* Srow = Sl + (long)row * NSEQ;
  for (int t = lane; t < NSEQ; t += 64) srow[w][t] = Srow[t];
  __syncthreads();
  const float* Vb = Vw + ((long)b << 15);    // b * N * DH
  float acc = 0.f;
  #pragma unroll 8
  for (int j = 0; j < NSEQ; ++j) {
    const float att = __expf(srow[w][j] - mrow[j]) * rsrow[j];
    acc = fmaf(att, Vb[(long)j * DHO + lane], acc);
  }
  hout[(long)row * DHO + lane] = acc;
}

// ---------------------------------------------------------------------------
extern "C" void kernel_launch(void* const* d_in, const int* in_sizes, int n_in,
                              void* d_out, int out_size, void* d_ws, size_t ws_size,
                              hipStream_t stream) {
  const float* h   = (const float*)d_in[0];
  const float* e   = (const float*)d_in[1];
  const float* Wq  = (const float*)d_in[2];
  const float* bq  = (const float*)d_in[3];
  const float* Wk  = (const float*)d_in[4];
  const float* bk  = (const float*)d_in[5];
  const float* Wv  = (const float*)d_in[6];
  const float* bv  = (const float*)d_in[7];
  const float* We  = (const float*)d_in[8];
  const float* be  = (const float*)d_in[9];
  const float* Wni = (const float*)d_in[10];
  const float* bni = (const float*)d_in[11];
  const float* Wnj = (const float*)d_in[12];
  const float* bnj = (const float*)d_in[13];

  float* out  = (float*)d_out;
  float* hout = out;                               // [B,N,DH]
  float* eout = out + (long)BATCH * NSEQ * DHO;    // [B,N,N,DH]

  float* ws    = (float*)d_ws;
  float* Qw    = ws + OFF_Q;
  float* Kw    = ws + OFF_K;
  float* Vw    = ws + OFF_V;
  float* Niw   = ws + OFF_NI;
  float* Njw   = ws + OFF_NJ;
  float* Sl    = ws + OFF_S;
  float* colm  = ws + OFF_CM;
  float* colrs = ws + OFF_CRS;

  k1_proj<<<BATCH * NSEQ, 320, 0, stream>>>(h, Wq, bq, Wk, bk, Wv, bv,
                                            Wni, bni, Wnj, bnj,
                                            Qw, Kw, Vw, Niw, Njw);
  k2_eout_att<<<K2_BLOCKS, 256, 0, stream>>>(e, We, be, Qw, Kw, Niw, Njw, eout, Sl);
  k3_colstats<<<BATCH * (NSEQ / 16), 256, 0, stream>>>(Sl, colm, colrs);
  k4_hout<<<(BATCH * NSEQ) / 4, 256, 0, stream>>>(Sl, colm, colrs, Vw, hout);
}